// Round 1
// baseline (719.651 us; speedup 1.0000x reference)
//
#include <hip/hip_runtime.h>

#define STEPS   200
#define NT      199        // STEPS - 1 drive/scan steps
#define BATCH   512
#define IN_DIM  784
#define OUT_DIM 10

__global__ __launch_bounds__(256) void snn_fwd_kernel(
    const float* __restrict__ x,   // [BATCH, IN_DIM, STEPS]
    const float* __restrict__ w,   // [OUT_DIM, IN_DIM]
    float* __restrict__ out)       // [BATCH, OUT_DIM]
{
    __shared__ float w_lds[IN_DIM * OUT_DIM];   // [i][o] transposed weights, 31.4 KB
    __shared__ float drive[NT * OUT_DIM];       // [t][o], 8 KB

    const int b   = blockIdx.x;
    const int tid = threadIdx.x;

    // Stage weights transposed: w_lds[i*OUT+o] = w[o*IN+i].
    // Global reads of w are coalesced; LDS reads later are wave-uniform broadcasts.
    for (int idx = tid; idx < IN_DIM * OUT_DIM; idx += 256) {
        int o = idx / IN_DIM;
        int i = idx - o * IN_DIM;
        w_lds[i * OUT_DIM + o] = w[idx];
    }
    __syncthreads();

    // Phase 1: drive[t][o] = sum_i x[b,i,t] * w[o,i].
    // Thread t owns time bin t; lane-consecutive t -> coalesced global loads.
    const int t = tid;
    if (t < NT) {
        float acc[OUT_DIM];
        #pragma unroll
        for (int o = 0; o < OUT_DIM; ++o) acc[o] = 0.0f;

        const float* xb = x + (size_t)b * IN_DIM * STEPS + t;
        #pragma unroll 4
        for (int i = 0; i < IN_DIM; ++i) {
            float xv = xb[(size_t)i * STEPS];
            if (xv != 0.0f) {       // spikes are exactly 1.0; ~2% density
                #pragma unroll
                for (int o = 0; o < OUT_DIM; ++o)
                    acc[o] += w_lds[i * OUT_DIM + o];
            }
        }
        #pragma unroll
        for (int o = 0; o < OUT_DIM; ++o)
            drive[t * OUT_DIM + o] = acc[o];
    }
    __syncthreads();

    // Phase 2: LIF scan + first-spike time, one thread per output neuron.
    if (tid < OUT_DIM) {
        const int o = tid;
        const float a_m = 1.0f - 0.1f / 20.0f;   // 0.995
        const float b_m = 0.1f / 20.0f;          // 0.005
        const float a_s = 1.0f - 0.1f / 5.0f;    // 0.98

        float V = 0.0f, I = 0.0f;
        int fst = 0;
        for (int s = 0; s < NT; ++s) {
            float Vn = a_m * V + b_m * I;        // uses OLD I (pre-drive), per reference
            I = a_s * I + drive[s * OUT_DIM + o];
            if (Vn > 1.0f) {
                if (fst == 0) fst = s + 1;       // spike lands at output time s+1 (t=0 padded)
                V = 0.0f;                        // reset on spike
            } else {
                V = Vn;
            }
        }
        out[b * OUT_DIM + o] = (fst == 0) ? (float)(STEPS - 1) : (float)fst;
    }
}

extern "C" void kernel_launch(void* const* d_in, const int* in_sizes, int n_in,
                              void* d_out, int out_size, void* d_ws, size_t ws_size,
                              hipStream_t stream) {
    const float* x = (const float*)d_in[0];   // [512, 784, 200] fp32
    const float* w = (const float*)d_in[1];   // [10, 784] fp32
    float* out = (float*)d_out;               // [512, 10] fp32
    snn_fwd_kernel<<<dim3(BATCH), dim3(256), 0, stream>>>(x, w, out);
}

// Round 2
// 568.256 us; speedup vs baseline: 1.2664x; 1.2664x over previous
//
#include <hip/hip_runtime.h>

#define STEPS   200
#define NT      199
#define BATCH   512
#define IN_DIM  784
#define OUT_DIM 10
#define NCHUNK  4
#define CHUNK   (IN_DIM / NCHUNK)   // 196, divisible by 4
#define WT_STRIDE 16                // pad 10 -> 16 for aligned wide scalar loads

// Setup: transpose + pad weights into workspace: wt[i][o] = w[o][i].
__global__ __launch_bounds__(256) void pack_weights(
    const float* __restrict__ w, float* __restrict__ wt)
{
    int i = blockIdx.x * 256 + threadIdx.x;
    if (i < IN_DIM) {
        #pragma unroll
        for (int o = 0; o < OUT_DIM; ++o)
            wt[i * WT_STRIDE + o] = w[o * IN_DIM + i];
    }
}

// One block per batch element. 1024 threads = 4 input-chunks x 256 time-lanes.
// __launch_bounds__(1024, 8): 8 waves/EU -> 2 blocks/CU -> 32 waves/CU, VGPR<=64.
__global__ __launch_bounds__(1024, 8) void snn_fwd(
    const float* __restrict__ x,    // [BATCH, IN_DIM, STEPS]
    const float* __restrict__ wt,   // [IN_DIM, WT_STRIDE] transposed weights
    float* __restrict__ out)        // [BATCH, OUT_DIM]
{
    __shared__ float dlds[NCHUNK][NT][OUT_DIM];   // partial drives, ~31 KB

    const int b   = blockIdx.x;
    const int tid = threadIdx.x;
    const int c   = tid >> 8;      // input chunk 0..3
    const int t   = tid & 255;     // time bin, active if < NT

    if (t < NT) {
        float acc[OUT_DIM];
        #pragma unroll
        for (int o = 0; o < OUT_DIM; ++o) acc[o] = 0.0f;

        const float* xb = x + (size_t)b * IN_DIM * STEPS + t;
        const int i0 = c * CHUNK;

        for (int ib = 0; ib < CHUNK; ib += 4) {
            // batch 4 independent global loads first (MLP=4), then consume
            float xv[4];
            #pragma unroll
            for (int k = 0; k < 4; ++k)
                xv[k] = xb[(size_t)(i0 + ib + k) * STEPS];   // lane-coalesced over t
            #pragma unroll
            for (int k = 0; k < 4; ++k) {
                const float* wp = wt + (size_t)(i0 + ib + k) * WT_STRIDE; // uniform addr -> s_load
                #pragma unroll
                for (int o = 0; o < OUT_DIM; ++o)
                    acc[o] = fmaf(xv[k], wp[o], acc[o]);     // xv is 0/1: exact
            }
        }
        #pragma unroll
        for (int o = 0; o < OUT_DIM; ++o)
            dlds[c][t][o] = acc[o];
    }
    __syncthreads();

    // LIF scan + first-spike time: one thread per output neuron.
    // Fixed-order chunk reduction keeps fp summation deterministic.
    if (tid < OUT_DIM) {
        const int o = tid;
        const float a_m = 0.995f;   // 1 - DT/TAU_M
        const float b_m = 0.005f;   // DT/TAU_M
        const float a_s = 0.98f;    // 1 - DT/TAU_S

        float V = 0.0f, I = 0.0f;
        int fst = 0;
        for (int s = 0; s < NT; ++s) {
            float drv = ((dlds[0][s][o] + dlds[1][s][o]) + dlds[2][s][o]) + dlds[3][s][o];
            float Vn = a_m * V + b_m * I;   // old I, per reference ordering
            I = a_s * I + drv;
            if (Vn > 1.0f) {
                if (fst == 0) fst = s + 1;  // +1: output is zero-padded at t=0
                V = 0.0f;
            } else {
                V = Vn;
            }
        }
        out[b * OUT_DIM + o] = (fst == 0) ? (float)(STEPS - 1) : (float)fst;
    }
}

extern "C" void kernel_launch(void* const* d_in, const int* in_sizes, int n_in,
                              void* d_out, int out_size, void* d_ws, size_t ws_size,
                              hipStream_t stream) {
    const float* x = (const float*)d_in[0];   // [512, 784, 200] fp32
    const float* w = (const float*)d_in[1];   // [10, 784] fp32
    float* out = (float*)d_out;               // [512, 10] fp32
    float* wt  = (float*)d_ws;                // [784][16] floats = 50 KB

    pack_weights<<<dim3((IN_DIM + 255) / 256), dim3(256), 0, stream>>>(w, wt);
    snn_fwd<<<dim3(BATCH), dim3(1024), 0, stream>>>(x, wt, out);
}

// Round 3
// 437.307 us; speedup vs baseline: 1.6456x; 1.2994x over previous
//
#include <hip/hip_runtime.h>

#define STEPS   200
#define NT      199
#define BATCH   512
#define IN_DIM  784
#define OUT_DIM 10
#define NCHUNK  4
#define CHUNK   (IN_DIM / NCHUNK)   // 196
#define WS      12                  // weight LDS stride: 48 B, 16 B aligned

// One block per batch element. 1024 threads = 4 input-chunks x 256 time-lanes.
// LDS: 784*12*4 = 37.6 KB weights + 4*199*10*4 = 31.8 KB drive = 69.4 KB
//   -> 2 blocks/CU (160 KB), 32 waves/CU.
__global__ __launch_bounds__(1024, 8) void snn_fwd(
    const float* __restrict__ x,    // [BATCH, IN_DIM, STEPS]
    const float* __restrict__ w,    // [OUT_DIM, IN_DIM]
    float* __restrict__ out)        // [BATCH, OUT_DIM]
{
    __shared__ float w_lds[IN_DIM * WS];
    __shared__ float dlds[NCHUNK][NT][OUT_DIM];

    const int b   = blockIdx.x;
    const int tid = threadIdx.x;
    const int c   = tid >> 8;      // input chunk 0..3
    const int t   = tid & 255;     // time bin, active if < NT

    // Stage weights transposed: w_lds[i*WS+o] = w[o*IN+i]. Coalesced global reads.
    for (int idx = tid; idx < IN_DIM * OUT_DIM; idx += 1024) {
        int o = idx / IN_DIM;
        int i = idx - o * IN_DIM;
        w_lds[i * WS + o] = w[idx];
    }
    __syncthreads();

    if (t < NT) {
        float acc[OUT_DIM];
        #pragma unroll
        for (int o = 0; o < OUT_DIM; ++o) acc[o] = 0.0f;

        const float* xb = x + (size_t)b * IN_DIM * STEPS + t;
        const int i0 = c * CHUNK;

        // 24 groups of 8 + tail of 4; ascending i preserves exact sum order.
        #define CONSUME(ii, xv)                                                  \
            do {                                                                 \
                const float4 w0 = *(const float4*)&w_lds[(ii) * WS + 0];         \
                const float4 w1 = *(const float4*)&w_lds[(ii) * WS + 4];         \
                const float2 w2 = *(const float2*)&w_lds[(ii) * WS + 8];         \
                acc[0] = fmaf(xv, w0.x, acc[0]);                                 \
                acc[1] = fmaf(xv, w0.y, acc[1]);                                 \
                acc[2] = fmaf(xv, w0.z, acc[2]);                                 \
                acc[3] = fmaf(xv, w0.w, acc[3]);                                 \
                acc[4] = fmaf(xv, w1.x, acc[4]);                                 \
                acc[5] = fmaf(xv, w1.y, acc[5]);                                 \
                acc[6] = fmaf(xv, w1.z, acc[6]);                                 \
                acc[7] = fmaf(xv, w1.w, acc[7]);                                 \
                acc[8] = fmaf(xv, w2.x, acc[8]);                                 \
                acc[9] = fmaf(xv, w2.y, acc[9]);                                 \
            } while (0)

        for (int ib = 0; ib < 192; ib += 8) {
            float xv[8];
            #pragma unroll
            for (int k = 0; k < 8; ++k)          // 8 independent loads in flight
                xv[k] = xb[(size_t)(i0 + ib + k) * STEPS];
            #pragma unroll
            for (int k = 0; k < 8; ++k)
                CONSUME(i0 + ib + k, xv[k]);
        }
        {   // tail: i = i0+192 .. i0+195
            float xv[4];
            #pragma unroll
            for (int k = 0; k < 4; ++k)
                xv[k] = xb[(size_t)(i0 + 192 + k) * STEPS];
            #pragma unroll
            for (int k = 0; k < 4; ++k)
                CONSUME(i0 + 192 + k, xv[k]);
        }
        #undef CONSUME

        #pragma unroll
        for (int o = 0; o < OUT_DIM; ++o)
            dlds[c][t][o] = acc[o];
    }
    __syncthreads();

    // LIF scan + first-spike time: one thread per output neuron.
    // Fixed-order chunk reduction keeps fp summation deterministic (matches R2).
    if (tid < OUT_DIM) {
        const int o = tid;
        const float a_m = 0.995f;   // 1 - DT/TAU_M
        const float b_m = 0.005f;   // DT/TAU_M
        const float a_s = 0.98f;    // 1 - DT/TAU_S

        float V = 0.0f, I = 0.0f;
        int fst = 0;
        for (int s = 0; s < NT; ++s) {
            float drv = ((dlds[0][s][o] + dlds[1][s][o]) + dlds[2][s][o]) + dlds[3][s][o];
            float Vn = a_m * V + b_m * I;   // old I, per reference ordering
            I = a_s * I + drv;
            if (Vn > 1.0f) {
                if (fst == 0) fst = s + 1;  // +1: output zero-padded at t=0
                V = 0.0f;
            } else {
                V = Vn;
            }
        }
        out[b * OUT_DIM + o] = (fst == 0) ? (float)(STEPS - 1) : (float)fst;
    }
}

extern "C" void kernel_launch(void* const* d_in, const int* in_sizes, int n_in,
                              void* d_out, int out_size, void* d_ws, size_t ws_size,
                              hipStream_t stream) {
    const float* x = (const float*)d_in[0];   // [512, 784, 200] fp32
    const float* w = (const float*)d_in[1];   // [10, 784] fp32
    float* out = (float*)d_out;               // [512, 10] fp32
    snn_fwd<<<dim3(BATCH), dim3(1024), 0, stream>>>(x, w, out);
}